// Round 5
// baseline (356.661 us; speedup 1.0000x reference)
//
#include <hip/hip_runtime.h>

typedef __attribute__((ext_vector_type(8))) short bfrag;   // 8 bf16 = 4 VGPR
typedef __attribute__((ext_vector_type(4))) float ffrag;   // MFMA 16x16 acc

#define NPAIR 24

__device__ __forceinline__ unsigned short f2b(float f) {   // f32 -> bf16 RTNE
    unsigned u = __builtin_bit_cast(unsigned, f);
    return (unsigned short)((u + 0x7FFFu + ((u >> 16) & 1u)) >> 16);
}
__device__ __forceinline__ unsigned pk2(float a, float b) {
    return (unsigned)f2b(a) | ((unsigned)f2b(b) << 16);
}

// Separable mixed-Gaussian grouped conv via two banded-MFMA passes.
// Pair p=0..23: c=p>>3, k=p-c. Tap factor a_g[j] = W[g,k,10,j]/sqrt(W[g,k,10,10]).
// P2: t_g[r][c] = w_g * sum_j a_g[j] x[r][c+j]   (A = x rows, B = banded taps)
// P3: out[y][c] = sum_g sum_i a_g[i] t_g[i+y][c] (A = t cols, B = banded taps)
// Band fragments depend only on d = 2*step - group in {-1,0,1,2} -> one table
// serves both passes and both operand roles (A/B lane maps are identical).
// R5 = R3 (222us) + ONLY the P3 operand swap + float4 fan-out (bisecting R4's
// regression; R4 also changed staging, which is reverted here).
__global__ __launch_bounds__(256, 3) void gcm_mfma(
    const float* __restrict__ x,
    const float* __restrict__ wgt,
    const float* __restrict__ bw,
    float* __restrict__ out)
{
    __shared__ __align__(16) short sx[96 * 104];      // x tile bf16, stride 104
    __shared__ __align__(16) short st[64 * 104];      // t transposed [col][row]
    __shared__ __align__(16) short tab[4 * 4 * 64 * 8]; // [g][d+1][lane][8]
    __shared__ float tapF[4 * 96];                    // padded taps, f32

    const int tid  = threadIdx.x;
    const int lane = tid & 63;
    const int wv   = tid >> 6;        // wave id == column-group
    const int ln   = lane & 15;
    const int lq   = lane >> 4;

    // XCD-aware bijective swizzle (12288 = 8 * 1536)
    const int phys = blockIdx.x;
    const int logical = (phys & 7) * 1536 + (phys >> 3);
    const int bz  = logical >> 6;
    const int rem = logical & 63;
    const int by = rem >> 3, bx = rem & 7;
    const int b = bz / NPAIR;
    const int p = bz - b * NPAIR;
    const int c = p >> 3;
    const int k = p - c;

    // ---- padded tap factors (f32), index u = idx-32 in [-32, 64)
    for (int i = tid; i < 4 * 96; i += 256) {
        const int g = i / 96, u = (i - g * 96) - 32;
        float v = 0.f;
        if ((unsigned)u < 21u) {
            const float* Wk = bw + (size_t)(g * 22 + k) * 441;
            v = Wk[210 + u] / sqrtf(Wk[220]);
        }
        tapF[i] = v;
    }

    // ---- stage x tile -> bf16 (R3 path, verbatim)
    const int gx0 = bx * 64 - 10, gy0 = by * 64 - 10;
    const float* xc = x + (size_t)(b * 3 + c) * (512 * 512);
    for (int i = tid; i < 96 * 52; i += 256) {
        const int row = i / 52, cp = i - row * 52;
        const int gy = gy0 + row;
        const int gx = gx0 + 2 * cp;
        float v0 = 0.f, v1 = 0.f;
        if (row < 84 && (unsigned)gy < 512u) {
            if ((unsigned)gx < 512u)       v0 = xc[gy * 512 + gx];
            if ((unsigned)(gx + 1) < 512u) v1 = xc[gy * 512 + gx + 1];
        }
        ((unsigned*)sx)[i] = pk2(v0, v1);
    }
    __syncthreads();

    // ---- band-fragment table: entry[(g,di,l)][j] = a_g[16(di-1)+8*(l>>4)+j-(l&15)]
    for (int e = tid; e < 4 * 4 * 64; e += 256) {
        const int g  = e >> 8;
        const int di = (e >> 6) & 3;
        const int l  = e & 63;
        const int base = 16 * (di - 1) + 8 * (l >> 4) - (l & 15) + 32;
        const float* tp = &tapF[g * 96];
        *(uint4*)&tab[e * 8] = make_uint4(
            pk2(tp[base + 0], tp[base + 1]), pk2(tp[base + 2], tp[base + 3]),
            pk2(tp[base + 4], tp[base + 5]), pk2(tp[base + 6], tp[base + 7]));
    }

    // ---- preload this wave's x fragments: rows 16rg+ln, k-steps {s0, s0+1}
    const int s0 = wv >> 1;
    bfrag xa[6][2];
    #pragma unroll
    for (int rg = 0; rg < 6; ++rg) {
        xa[rg][0] = *(const bfrag*)&sx[(16 * rg + ln) * 104 + 32 * s0 + 8 * lq];
        xa[rg][1] = *(const bfrag*)&sx[(16 * rg + ln) * 104 + 32 * (s0 + 1) + 8 * lq];
    }
    __syncthreads();   // tab ready

    ffrag acc3[4];
    #pragma unroll
    for (int yg = 0; yg < 4; ++yg) acc3[yg] = ffrag{0.f, 0.f, 0.f, 0.f};

    #pragma unroll 1
    for (int g = 0; g < 4; ++g) {
        const float wg = wgt[(b * 4 + g) * 22 + k];
        // P2: horizontal conv -> t (transposed store), scaled by wg
        const bfrag tb0 = *(const bfrag*)&tab[((g * 4 + (2 * s0 - wv + 1)) * 64 + lane) * 8];
        const bfrag tb1 = *(const bfrag*)&tab[((g * 4 + (2 * s0 + 2 - wv + 1)) * 64 + lane) * 8];
        #pragma unroll
        for (int rg = 0; rg < 6; ++rg) {
            ffrag a = ffrag{0.f, 0.f, 0.f, 0.f};
            a = __builtin_amdgcn_mfma_f32_16x16x32_bf16(xa[rg][0], tb0, a, 0, 0, 0);
            a = __builtin_amdgcn_mfma_f32_16x16x32_bf16(xa[rg][1], tb1, a, 0, 0, 0);
            // lane holds rows r=16rg+4lq+{0..3}, col c=16wv+ln
            *(uint2*)&st[(16 * wv + ln) * 104 + 16 * rg + 4 * lq] =
                make_uint2(pk2(a.x * wg, a.y * wg), pk2(a.z * wg, a.w * wg));
        }
        __syncthreads();
        // P3: vertical conv; A = t columns, B = banded taps -> D m-dim is cols
        bfrag tbv[3];
        #pragma unroll
        for (int s = 0; s < 3; ++s)
            tbv[s] = *(const bfrag*)&st[(16 * wv + ln) * 104 + 32 * s + 8 * lq];
        #pragma unroll
        for (int yg = 0; yg < 4; ++yg) {
            const int sa = yg >> 1;
            #pragma unroll
            for (int si = 0; si < 2; ++si) {
                const int s  = sa + si;
                const int di = 2 * s - yg + 1;
                const bfrag ta = *(const bfrag*)&tab[((g * 4 + di) * 64 + lane) * 8];
                acc3[yg] = __builtin_amdgcn_mfma_f32_16x16x32_bf16(tbv[s], ta, acc3[yg], 0, 0, 0);
            }
        }
        if (g < 3) __syncthreads();  // before next g overwrites st
    }

    // ---- fan-out stores: lane holds out[y=16yg+ln][c=16wv+4lq+{0..3}] -> float4
    const int oS = (3 * k > 22 * c) ? 3 * k : 22 * c;
    const int t1 = 3 * k + 2, t2 = 22 * c + 21;
    const int oE = (t1 < t2) ? t1 : t2;
    const int gxo = bx * 64 + 16 * wv + 4 * lq;
    #pragma unroll
    for (int yg = 0; yg < 4; ++yg) {
        const int gy = by * 64 + 16 * yg + ln;
        for (int o = oS; o <= oE; ++o) {
            float* ob = out + ((size_t)(b * 66 + o) * 512 + gy) * 512 + gxo;
            *(float4*)ob = make_float4(acc3[yg].x, acc3[yg].y, acc3[yg].z, acc3[yg].w);
        }
    }
}

extern "C" void kernel_launch(void* const* d_in, const int* in_sizes, int n_in,
                              void* d_out, int out_size, void* d_ws, size_t ws_size,
                              hipStream_t stream) {
    const float* x   = (const float*)d_in[0];
    const float* wgt = (const float*)d_in[1];
    const float* bw  = (const float*)d_in[2];
    float* out = (float*)d_out;
    gcm_mfma<<<dim3(8 * 8 * 8 * NPAIR), 256, 0, stream>>>(x, wgt, bw, out);
}

// Round 6
// 158.653 us; speedup vs baseline: 2.2481x; 2.2481x over previous
//
#include <hip/hip_runtime.h>

typedef __attribute__((ext_vector_type(8))) short bfrag;   // 8 bf16 = 4 VGPR
typedef __attribute__((ext_vector_type(4))) float ffrag;   // MFMA 16x16 acc

#define NPAIR 24
#define PR 544            // padded rows per channel (532 used + 12 slack)
#define PC 544            // padded cols (532 used + 12 slack)
#define XPLANE (PR * PC)  // bf16 elements per channel plane

__device__ __forceinline__ unsigned short f2b(float f) {   // f32 -> bf16 RTNE
    unsigned u = __builtin_bit_cast(unsigned, f);
    return (unsigned short)((u + 0x7FFFu + ((u >> 16) & 1u)) >> 16);
}
__device__ __forceinline__ unsigned pk2(float a, float b) {
    return (unsigned)f2b(a) | ((unsigned)f2b(b) << 16);
}

// ---------- prep 1: x -> zero-padded bf16 [24][544][544] (halo baked in) ----
__global__ __launch_bounds__(256) void prep_pad(
    const float* __restrict__ x, unsigned short* __restrict__ px)
{
    int t = blockIdx.x * 256 + threadIdx.x;    // 24*544*68 = 887808 threads
    const int pc8 = t % (PC / 8);  t /= (PC / 8);
    const int pr  = t % PR;        t /= PR;
    const int bc  = t;                          // (b*3+c) 0..23
    const int sr  = pr - 10;
    const float* xp = x + (size_t)bc * (512 * 512);
    unsigned o[4];
    #pragma unroll
    for (int h = 0; h < 4; ++h) {
        const int c0 = pc8 * 8 + 2 * h - 10;
        float v0 = 0.f, v1 = 0.f;
        if ((unsigned)sr < 512u) {
            if ((unsigned)c0 < 512u)       v0 = xp[sr * 512 + c0];
            if ((unsigned)(c0 + 1) < 512u) v1 = xp[sr * 512 + c0 + 1];
        }
        o[h] = pk2(v0, v1);
    }
    *(uint4*)&px[(size_t)bc * XPLANE + pr * PC + pc8 * 8] =
        make_uint4(o[0], o[1], o[2], o[3]);
}

// ---------- prep 2: band-fragment table tabG[k][g][di][lane][8] -------------
// entry value j: a_{g,k}[16(di-1) + 8*(l>>4) - (l&15) + j], zero outside [0,21)
__global__ __launch_bounds__(256) void prep_tab(
    const float* __restrict__ bw, unsigned short* __restrict__ tabG)
{
    const int kk = blockIdx.x >> 2;          // 0..21
    const int g  = blockIdx.x & 3;
    const int di = threadIdx.x >> 6;
    const int l  = threadIdx.x & 63;
    const float* Wk = bw + (size_t)(g * 22 + kk) * 441;
    const float sq = sqrtf(Wk[220]);
    const int base = 16 * (di - 1) + 8 * (l >> 4) - (l & 15);
    unsigned o[4];
    #pragma unroll
    for (int h = 0; h < 4; ++h) {
        const int u0 = base + 2 * h, u1 = u0 + 1;
        float v0 = 0.f, v1 = 0.f;
        if ((unsigned)u0 < 21u) v0 = Wk[210 + u0] / sq;
        if ((unsigned)u1 < 21u) v1 = Wk[210 + u1] / sq;
        o[h] = pk2(v0, v1);
    }
    *(uint4*)&tabG[((size_t)blockIdx.x * 256 + threadIdx.x) * 8] =
        make_uint4(o[0], o[1], o[2], o[3]);
}

// ---------- main: two banded-MFMA passes, st-only LDS (13 KB) ---------------
// P2: t_g[r][c] = w_g * sum_j a_g[j] x[r][c+j]   (A = x rows, B = banded taps)
// P3: out[y][c] = sum_g sum_i a_g[i] t_g[i+y][c] (A = banded taps, B = t cols)
// R3's proven compute + scalar fan-out stores; sx/tab/tapF moved to prep.
__global__ __launch_bounds__(256, 5) void gcm_main(
    const unsigned short* __restrict__ px,
    const unsigned short* __restrict__ tabG,
    const float* __restrict__ wgt,
    float* __restrict__ out)
{
    __shared__ __align__(16) short st[64 * 104];   // t transposed [col][row]

    const int tid  = threadIdx.x;
    const int lane = tid & 63;
    const int wv   = tid >> 6;
    const int ln   = lane & 15;
    const int lq   = lane >> 4;

    // XCD-aware bijective swizzle (12288 = 8 * 1536)
    const int phys = blockIdx.x;
    const int logical = (phys & 7) * 1536 + (phys >> 3);
    const int bz  = logical >> 6;
    const int rem = logical & 63;
    const int by = rem >> 3, bx = rem & 7;
    const int b = bz / NPAIR;
    const int p = bz - b * NPAIR;
    const int c = p >> 3;
    const int k = p - c;

    // ---- x fragments direct from padded bf16 global (no bounds checks)
    const int s0 = wv >> 1;
    const unsigned short* xb = px + (size_t)(b * 3 + c) * XPLANE
                             + (by * 64 + ln) * PC + bx * 64 + 32 * s0 + 8 * lq;
    bfrag xa[6][2];
    #pragma unroll
    for (int rg = 0; rg < 6; ++rg) {
        xa[rg][0] = *(const bfrag*)(xb + 16 * rg * PC);
        xa[rg][1] = *(const bfrag*)(xb + 16 * rg * PC + 32);
    }

    const unsigned short* tk = tabG + (size_t)k * (16 * 64 * 8);
    const float* wrow = wgt + (b * 4) * 22 + k;

    ffrag acc3[4];
    #pragma unroll
    for (int yg = 0; yg < 4; ++yg) acc3[yg] = ffrag{0.f, 0.f, 0.f, 0.f};

    #pragma unroll 1
    for (int g = 0; g < 4; ++g) {
        const float wg = wrow[g * 22];
        // P2: horizontal conv -> t (transposed store), scaled by wg
        const bfrag tb0 = *(const bfrag*)&tk[((g * 4 + (2 * s0 - wv + 1)) * 64 + lane) * 8];
        const bfrag tb1 = *(const bfrag*)&tk[((g * 4 + (2 * s0 + 2 - wv + 1)) * 64 + lane) * 8];
        #pragma unroll
        for (int rg = 0; rg < 6; ++rg) {
            ffrag a = ffrag{0.f, 0.f, 0.f, 0.f};
            a = __builtin_amdgcn_mfma_f32_16x16x32_bf16(xa[rg][0], tb0, a, 0, 0, 0);
            a = __builtin_amdgcn_mfma_f32_16x16x32_bf16(xa[rg][1], tb1, a, 0, 0, 0);
            // lane holds rows r=16rg+4lq+{0..3}, col c=16wv+ln
            *(uint2*)&st[(16 * wv + ln) * 104 + 16 * rg + 4 * lq] =
                make_uint2(pk2(a.x * wg, a.y * wg), pk2(a.z * wg, a.w * wg));
        }
        __syncthreads();
        // P3: vertical conv (A = banded taps, B = t cols) -- R3 operand order
        bfrag tbv[3];
        #pragma unroll
        for (int s = 0; s < 3; ++s)
            tbv[s] = *(const bfrag*)&st[(16 * wv + ln) * 104 + 32 * s + 8 * lq];
        #pragma unroll
        for (int yg = 0; yg < 4; ++yg) {
            const int sa = yg >> 1;
            #pragma unroll
            for (int si = 0; si < 2; ++si) {
                const int s  = sa + si;
                const int di = 2 * s - yg + 1;
                const bfrag ta = *(const bfrag*)&tk[((g * 4 + di) * 64 + lane) * 8];
                acc3[yg] = __builtin_amdgcn_mfma_f32_16x16x32_bf16(ta, tbv[s], acc3[yg], 0, 0, 0);
            }
        }
        if (g < 3) __syncthreads();  // before next g overwrites st
    }

    // ---- fan-out stores (R3's proven scalar path)
    const int oS = (3 * k > 22 * c) ? 3 * k : 22 * c;
    const int t1 = 3 * k + 2, t2 = 22 * c + 21;
    const int oE = (t1 < t2) ? t1 : t2;
    const int gxo = bx * 64 + 16 * wv + ln;
    #pragma unroll
    for (int yg = 0; yg < 4; ++yg) {
        const int gy = by * 64 + 16 * yg + 4 * lq;
        for (int o = oS; o <= oE; ++o) {
            float* ob = out + ((size_t)(b * 66 + o) * 512 + gy) * 512 + gxo;
            ob[0]    = acc3[yg].x;
            ob[512]  = acc3[yg].y;
            ob[1024] = acc3[yg].z;
            ob[1536] = acc3[yg].w;
        }
    }
}

extern "C" void kernel_launch(void* const* d_in, const int* in_sizes, int n_in,
                              void* d_out, int out_size, void* d_ws, size_t ws_size,
                              hipStream_t stream) {
    const float* x   = (const float*)d_in[0];
    const float* wgt = (const float*)d_in[1];
    const float* bw  = (const float*)d_in[2];
    float* out = (float*)d_out;

    unsigned short* px   = (unsigned short*)d_ws;                    // 14,204,928 B
    unsigned short* tabG = (unsigned short*)((char*)d_ws + (size_t)24 * XPLANE * 2);

    prep_pad<<<dim3(24 * PR * (PC / 8) / 256), 256, 0, stream>>>(x, px);
    prep_tab<<<dim3(88), 256, 0, stream>>>(bw, tabG);
    gcm_main<<<dim3(8 * 8 * 8 * NPAIR), 256, 0, stream>>>(px, tabG, wgt, out);
}